// Round 1
// baseline (442.795 us; speedup 1.0000x reference)
//
#include <hip/hip_runtime.h>
#include <math.h>

#define BS   8
#define CLS  4
#define CCH  256
#define HH   128
#define WW   128
#define HWSZ (HH * WW)   // 16384
#define LL   19
#define TKK  256
#define MHH  64
#define MWW  64

// ---------------------------------------------------------------------------
// Fused prep kernel, one block per (b,l):
//   tq[t]       = sum_c token[b,l,c] * W2[t,c]          (thread = t, in LDS)
//   t3t[b,o,l]  = sum_t token[b,l,t] * W3[o,t] + b3[o]  (thread = o; row pad 20)
//   u[b,l,c]    = (1/64) * sum_t W1[t,c] * tq[t]        (thread = c)
// 1/64 folds the cls-mean (1/4) and softmax scale (1/sqrt(256)=1/16).
// ---------------------------------------------------------------------------
__global__ __launch_bounds__(256) void k_prep(
    const float* __restrict__ token, const float* __restrict__ W1,
    const float* __restrict__ W2, const float* __restrict__ W3,
    const float* __restrict__ b3, float* __restrict__ u,
    float* __restrict__ t3t) {
  __shared__ float tok_s[TKK];
  __shared__ float tq_s[TKK];
  const int bl = blockIdx.x;           // b*LL + l
  const int b  = bl / LL;
  const int l  = bl - b * LL;
  const int t  = threadIdx.x;
  tok_s[t] = token[(size_t)bl * TKK + t];
  __syncthreads();
  const float4* w2r = (const float4*)(W2 + (size_t)t * TKK);
  const float4* w3r = (const float4*)(W3 + (size_t)t * TKK);
  float a2 = 0.f, a3 = 0.f;
#pragma unroll 8
  for (int i = 0; i < TKK / 4; ++i) {
    float4 x = w2r[i];
    float4 y = w3r[i];
    const float* ts = &tok_s[4 * i];
    a2 += x.x * ts[0] + x.y * ts[1] + x.z * ts[2] + x.w * ts[3];
    a3 += y.x * ts[0] + y.y * ts[1] + y.z * ts[2] + y.w * ts[3];
  }
  tq_s[t] = a2;
  t3t[((size_t)b * CCH + t) * 20 + l] = a3 + b3[t];
  __syncthreads();
  float s0 = 0.f, s1 = 0.f, s2 = 0.f, s3 = 0.f;
#pragma unroll 4
  for (int k = 0; k < TKK; k += 4) {
    s0 += W1[(k + 0) * CCH + t] * tq_s[k + 0];
    s1 += W1[(k + 1) * CCH + t] * tq_s[k + 1];
    s2 += W1[(k + 2) * CCH + t] * tq_s[k + 2];
    s3 += W1[(k + 3) * CCH + t] * tq_s[k + 3];
  }
  u[(size_t)bl * CCH + t] = (s0 + s1 + s2 + s3) * (1.0f / 64.0f);
}

// ---------------------------------------------------------------------------
// Main fused kernel, v3 (latency-bound fix):
//   grid = 2048 blocks = (b, 64-px half-row). 256 thr = 4 waves.
//   Wave wv owns channels [wv*64, wv*64+64); lane owns ONE pixel (float loads,
//   256 B/wave per (batch,channel) segment -> fully coalesced).
//   vs v2 (1024 blocks): grid was the occupancy cap (4 blk/CU * 4 waves =
//   16/32 waves = 50% max, measured 40%, HBM 2.7 TB/s, VALU 17% -> latency
//   bound). 2048 blocks + 25.3 KB LDS -> 6 blk/CU = 24 waves = 75% cap.
//   Phase 1 stages 32 loads (8 ch x 4 batches) before any dependent FMA.
//   Phase 4 reads t3 from LDS (overlaid on dead u_s region) as broadcast
//   ds_read_b128 instead of 19-deep s_load chains; residual batched 8-deep.
// ---------------------------------------------------------------------------
__global__ __launch_bounds__(256, 3) void k_main(
    const float* __restrict__ mask, const float* __restrict__ fea,
    const float* __restrict__ u, const float* __restrict__ t3t,
    float* __restrict__ out) {
  // sh_buf overlay: phase 1 = u_s[19][256] (4864 f), phase 4 = t3[256][20] (5120 f)
  __shared__ float4 sh_buf4[(CCH * 20) / 4];   // 20480 B, 16B aligned
  __shared__ float acc_s[LL][64];              // 4864 B
  float* sh_buf = (float*)sh_buf4;

  const int blk  = blockIdx.x;
  const int b    = blk & 7;          // b fastest: blocks sharing fea adjacent
  const int s    = blk >> 3;         // 0..255 = half-row id; n0 = s*64
  const int n0   = s * 64;
  const int t    = threadIdx.x;
  const int lane = t & 63;
  const int wv   = t >> 6;

  // stage u (coalesced) + zero the accumulator
#pragma unroll
  for (int l = 0; l < LL; ++l)
    sh_buf[l * CCH + t] = u[((size_t)b * LL + l) * CCH + t];
  for (int k = t; k < LL * 64; k += 256) ((float*)acc_s)[k] = 0.f;

  // nearest-upsampled mask value for this lane's pixel:
  // pixel n = s*64+lane -> h = s>>1, w = (s&1)*64+lane -> mrow = s>>2,
  // mcol = (s&1)*32 + (lane>>1)
  const int mrow = s >> 2;
  const int mcol = ((s & 1) << 5) + (lane >> 1);
  const size_t mbase = ((size_t)(b * CLS) * MHH + mrow) * MWW + mcol;
  const float m0 = mask[mbase];
  const float m1 = mask[mbase + 1 * MHH * MWW];
  const float m2 = mask[mbase + 2 * MHH * MWW];
  const float m3 = mask[mbase + 3 * MHH * MWW];

  __syncthreads();

  // fea batch indices: (4b+cl) % 8 == 4*(b&1) + cl
  const int f0 = (b & 1) * 4;
  const float* fb = fea + (size_t)f0 * CCH * HWSZ + n0 + lane;
  const int c0 = wv * 64;

  float facc[LL];
#pragma unroll
  for (int l = 0; l < LL; ++l) facc[l] = 0.f;

  for (int cc = 0; cc < 64; cc += 8) {
    const int c = c0 + cc;
    // 32 independent loads staged before any use: max in-flight per wave
    float v0[8], v1[8], v2[8], v3[8];
#pragma unroll
    for (int j = 0; j < 8; ++j) {
      const size_t o0 = (size_t)(c + j) * HWSZ;
      v0[j] = fb[o0];
      v1[j] = fb[o0 + (size_t)1 * CCH * HWSZ];
      v2[j] = fb[o0 + (size_t)2 * CCH * HWSZ];
      v3[j] = fb[o0 + (size_t)3 * CCH * HWSZ];
    }
    float q[8];
#pragma unroll
    for (int j = 0; j < 8; ++j)
      q[j] = v0[j] * m0 + v1[j] * m1 + v2[j] * m2 + v3[j] * m3;
#pragma unroll
    for (int l = 0; l < LL; ++l) {
      const float4 ua = *(const float4*)&sh_buf[l * CCH + c];      // broadcast
      const float4 ub = *(const float4*)&sh_buf[l * CCH + c + 4];  // broadcast
      facc[l] += q[0] * ua.x + q[1] * ua.y + q[2] * ua.z + q[3] * ua.w +
                 q[4] * ub.x + q[5] * ub.y + q[6] * ub.z + q[7] * ub.w;
    }
  }

  // cross-wave reduction: distinct addresses within a wave, 4-way across waves
#pragma unroll
  for (int l = 0; l < LL; ++l) atomicAdd(&acc_s[l][lane], facc[l]);
  __syncthreads();   // facc contributions in AND all u_s reads done

  // u_s region dead -> stage t3 slice for this b (5120 floats, coalesced)
  {
    const float* t3b = t3t + (size_t)b * CCH * 20;
    for (int k = t; k < CCH * 20; k += 256) sh_buf[k] = t3b[k];
  }
  // softmax over l, in-place (threads 0..63, one pixel each; stride-1 = free)
  if (t < 64) {
    float a[LL];
    float mx = -INFINITY;
#pragma unroll
    for (int l = 0; l < LL; ++l) { a[l] = acc_s[l][t]; mx = fmaxf(mx, a[l]); }
    float sum = 0.f;
    float e[LL];
#pragma unroll
    for (int l = 0; l < LL; ++l) { e[l] = __expf(a[l] - mx); sum += e[l]; }
    const float inv = 1.0f / sum;
#pragma unroll
    for (int l = 0; l < LL; ++l)
      acc_s[l][t] = (a[l] != 0.f) ? e[l] * inv : 0.f;  // replicate where(a!=0)
  }
  __syncthreads();

  // probs for this lane's pixel
  float p[LL];
#pragma unroll
  for (int l = 0; l < LL; ++l) p[l] = acc_s[l][lane];

  // phase 4: wave-uniform o-slice; t3 rows via broadcast LDS float4 reads
  const int wvu = __builtin_amdgcn_readfirstlane(wv);
  const int ob  = wvu * 64;
  const float* fres = fea + ((size_t)b * CCH + ob) * HWSZ + n0 + lane;
  float*       ores = out + ((size_t)b * CCH + ob) * HWSZ + n0 + lane;

  for (int i0 = 0; i0 < 64; i0 += 8) {
    float r[8];   // 8 residual loads in flight
#pragma unroll
    for (int j = 0; j < 8; ++j) r[j] = fres[(size_t)(i0 + j) * HWSZ];
#pragma unroll
    for (int j = 0; j < 8; ++j) {
      const int o = ob + i0 + j;
      const float4* tv = (const float4*)&sh_buf[o * 20];  // 80B rows, 16B aligned
      const float4 A = tv[0], B = tv[1], C = tv[2], D = tv[3], E = tv[4];
      const float sres =
          p[0]  * A.x + p[1]  * A.y + p[2]  * A.z + p[3]  * A.w +
          p[4]  * B.x + p[5]  * B.y + p[6]  * B.z + p[7]  * B.w +
          p[8]  * C.x + p[9]  * C.y + p[10] * C.z + p[11] * C.w +
          p[12] * D.x + p[13] * D.y + p[14] * D.z + p[15] * D.w +
          p[16] * E.x + p[17] * E.y + p[18] * E.z;
      ores[(size_t)(i0 + j) * HWSZ] = sres + r[j];
    }
  }
}

// ---------------------------------------------------------------------------
extern "C" void kernel_launch(void* const* d_in, const int* in_sizes, int n_in,
                              void* d_out, int out_size, void* d_ws, size_t ws_size,
                              hipStream_t stream) {
  (void)in_sizes; (void)n_in; (void)out_size; (void)ws_size;
  const float* mask  = (const float*)d_in[0];
  const float* fea   = (const float*)d_in[1];
  const float* token = (const float*)d_in[2];
  const float* W1    = (const float*)d_in[3];
  const float* W2    = (const float*)d_in[4];
  const float* W3    = (const float*)d_in[5];
  const float* b3    = (const float*)d_in[6];
  float* out = (float*)d_out;

  float* u   = (float*)d_ws;                 // BS*LL*CCH floats (38912)
  float* t3t = u + BS * LL * CCH;            // BS*CCH*20 floats (40960)

  k_prep<<<BS * LL, 256, 0, stream>>>(token, W1, W2, W3, b3, u, t3t);
  k_main<<<(HWSZ / 64) * BS, 256, 0, stream>>>(mask, fea, u, t3t, out);
}